// Round 4
// baseline (676.426 us; speedup 1.0000x reference)
//
#include <hip/hip_runtime.h>
#include <stdint.h>

#define Bb 8
#define Tt 2048
#define Cc 512

typedef __attribute__((ext_vector_type(8))) short short8;
typedef __attribute__((ext_vector_type(4))) float f32x4;

__device__ __forceinline__ float b2f(short s) {
  unsigned int x = ((unsigned int)(unsigned short)s) << 16;
  return __builtin_bit_cast(float, x);
}
__device__ __forceinline__ short f2b(float f) {
  unsigned int x = __builtin_bit_cast(unsigned int, f);
  x += 0x7fffu + ((x >> 16) & 1u);   // round-to-nearest-even
  return (short)(x >> 16);
}

// Async global->LDS 16B copy. LDS dest is wave-uniform base + lane*16.
__device__ __forceinline__ void async_copy16(const short* g, short* l) {
  __builtin_amdgcn_global_load_lds(
      (const __attribute__((address_space(1))) unsigned int*)g,
      (__attribute__((address_space(3))) unsigned int*)l,
      16, 0, 0);
}

// ---------------------------------------------------------------------------
// GEMM: C[m,n] = epilogue( sum_k A[m,k] * B[n,k] )   (B row-major N x K, bf16)
// MODE 0: A fp32 (manual convert-stage), C bf16, +bias[n]     (pointwise)
// MODE 1: A bf16 async,                  C bf16, *scale       (scores)
// MODE 2: A bf16 async,                  C bf16               (P@V)
// MODE 3: A bf16 async,                  C fp32, +bias+resid  (out proj)
// 128x128 tile, BK=64, 4 waves 2x2, wave tile 64x64 via 4x4 MFMA 16x16x32.
// LDS layout: 16B chunk (m,kc) at short-offset ((kc*128 + (m^kc))*8).
// Async staging recreates this layout by swizzling the GLOBAL source address
// per lane (kc=idx>>7, m=(idx&127)^kc) -> identical fetch set, conflict-free
// ds_read_b128 fragments, and single-instruction staging.
// ---------------------------------------------------------------------------
template<int MODE>
__global__ __launch_bounds__(256, 2)
void gemm_bt(const void* __restrict__ Av, const void* __restrict__ Bv,
             void* __restrict__ Cv, const float* __restrict__ bias,
             const float* __restrict__ resid,
             int M, int N, int K,
             long long sA, long long sB, long long sC, float scale)
{
  __shared__ __align__(16) short ldsA[128 * 64];
  __shared__ __align__(16) short ldsB[128 * 64];
  const int tid  = threadIdx.x;
  const int lane = tid & 63;
  const int wv   = tid >> 6;
  const int bm = blockIdx.y * 128;
  const int bn = blockIdx.x * 128;
  const long long zoA = (long long)blockIdx.z * sA;
  const long long zoB = (long long)blockIdx.z * sB;
  const long long zoC = (long long)blockIdx.z * sC;
  const int wm = (wv >> 1) << 6;
  const int wn = (wv & 1) << 6;

  f32x4 zero4 = {0.f, 0.f, 0.f, 0.f};
  f32x4 acc[4][4];
#pragma unroll
  for (int i = 0; i < 4; ++i)
#pragma unroll
    for (int j = 0; j < 4; ++j)
      acc[i][j] = zero4;

  // swizzled lane->(m,kc) mapping per staging round
  int s_kc[4], s_m[4];
#pragma unroll
  for (int r = 0; r < 4; ++r) {
    const int idx = r * 256 + tid;
    s_kc[r] = idx >> 7;
    s_m[r]  = (idx & 127) ^ s_kc[r];
  }
  const int sm  = tid >> 3;  // MODE 0 manual staging: row within round
  const int skc = tid & 7;

  for (int k0 = 0; k0 < K; k0 += 64) {
#pragma unroll
    for (int r = 0; r < 4; ++r) {
      short* wbase = &ldsB[(r * 256 + wv * 64) * 8];
      async_copy16((const short*)Bv + zoB + (size_t)(bn + s_m[r]) * K + k0 + s_kc[r] * 8,
                   wbase);
    }
    if constexpr (MODE == 0) {
#pragma unroll
      for (int r = 0; r < 4; ++r) {
        const int m = r * 32 + sm;
        const float* ap = (const float*)Av + zoA + (size_t)(bm + m) * K + k0 + skc * 8;
        float4 f0 = *(const float4*)ap;
        float4 f1 = *(const float4*)(ap + 4);
        short8 av;
        av[0] = f2b(f0.x); av[1] = f2b(f0.y); av[2] = f2b(f0.z); av[3] = f2b(f0.w);
        av[4] = f2b(f1.x); av[5] = f2b(f1.y); av[6] = f2b(f1.z); av[7] = f2b(f1.w);
        *(short8*)&ldsA[((skc << 7) + (m ^ skc)) << 3] = av;
      }
    } else {
#pragma unroll
      for (int r = 0; r < 4; ++r) {
        short* wbase = &ldsA[(r * 256 + wv * 64) * 8];
        async_copy16((const short*)Av + zoA + (size_t)(bm + s_m[r]) * K + k0 + s_kc[r] * 8,
                     wbase);
      }
    }
    __syncthreads();
#pragma unroll
    for (int kk = 0; kk < 2; ++kk) {
      const int kcr = (kk << 2) + (lane >> 4);
      short8 af[4], bfv[4];
#pragma unroll
      for (int i = 0; i < 4; ++i) {
        const int ma = wm + i * 16 + (lane & 15);
        const int nb = wn + i * 16 + (lane & 15);
        af[i]  = *(const short8*)&ldsA[((kcr << 7) + (ma ^ kcr)) << 3];
        bfv[i] = *(const short8*)&ldsB[((kcr << 7) + (nb ^ kcr)) << 3];
      }
#pragma unroll
      for (int i = 0; i < 4; ++i)
#pragma unroll
        for (int j = 0; j < 4; ++j)
          acc[i][j] = __builtin_amdgcn_mfma_f32_16x16x32_bf16(af[i], bfv[j], acc[i][j], 0, 0, 0);
    }
    __syncthreads();
  }

  // C/D layout: col = lane&15, row = (lane>>4)*4 + reg  [measured m89/m91]
#pragma unroll
  for (int i = 0; i < 4; ++i) {
    const int row0 = bm + wm + i * 16 + ((lane >> 4) << 2);
#pragma unroll
    for (int j = 0; j < 4; ++j) {
      const int n = bn + wn + j * 16 + (lane & 15);
      float badd = 0.f;
      if (MODE == 0 || MODE == 3) badd = bias[n];
#pragma unroll
      for (int r = 0; r < 4; ++r) {
        float val = acc[i][j][r];
        if (MODE == 1) val *= scale;
        if (MODE == 0) val += badd;
        if constexpr (MODE == 3) {
          val += badd + resid[zoC + (size_t)(row0 + r) * N + n];
          ((float*)Cv)[zoC + (size_t)(row0 + r) * N + n] = val;
        } else {
          ((short*)Cv)[zoC + (size_t)(row0 + r) * N + n] = f2b(val);
        }
      }
    }
  }
}

// ---------------------------------------------------------------------------
// One-shot weight/bias packing: fp32 -> bf16, proj pairs concatenated to N=1024.
// ---------------------------------------------------------------------------
__global__ __launch_bounds__(256)
void pack_all(const float* __restrict__ lw1a, const float* __restrict__ lw1b,
              const float* __restrict__ rw1a, const float* __restrict__ rw1b,
              const float* __restrict__ w3lf, const float* __restrict__ w3rf,
              const float* __restrict__ lb1a, const float* __restrict__ lb1b,
              const float* __restrict__ rb1a, const float* __restrict__ rb1b,
              short* __restrict__ Wl, short* __restrict__ Wr,
              short* __restrict__ W3l, short* __restrict__ W3r,
              float* __restrict__ BL, float* __restrict__ BR)
{
  const int i = blockIdx.x * 256 + threadIdx.x;
  if (i < 524288) {
    Wl[i] = f2b(i < 262144 ? lw1a[i] : lw1b[i - 262144]);
  } else if (i < 1048576) {
    const int j = i - 524288;
    Wr[j] = f2b(j < 262144 ? rw1a[j] : rw1b[j - 262144]);
  } else if (i < 1310720) {
    W3l[i - 1048576] = f2b(w3lf[i - 1048576]);
  } else if (i < 1572864) {
    W3r[i - 1310720] = f2b(w3rf[i - 1310720]);
  } else if (i < 1573888) {
    const int j = i - 1572864;
    BL[j] = j < 512 ? lb1a[j] : lb1b[j - 512];
  } else if (i < 1574912) {
    const int j = i - 1573888;
    BR[j] = j < 512 ? rb1a[j] : rb1b[j - 512];
  }
}

// ---------------------------------------------------------------------------
// Depthwise conv k=3 pad=1 over T. H row stride 1024, slice [colOff,colOff+512).
// ---------------------------------------------------------------------------
__global__ __launch_bounds__(256)
void dw_kernel(const short* __restrict__ H, const float* __restrict__ w2,
               const float* __restrict__ b2, short* __restrict__ out, int colOff)
{
  const int idx = blockIdx.x * 256 + threadIdx.x;   // over B*T*512/8
  const int c8 = idx & 63;
  const int bt = idx >> 6;
  const int t  = bt & (Tt - 1);
  const int c  = c8 << 3;
  const short* base = H + (size_t)bt * 1024 + colOff + c;
  short8 zz = {0, 0, 0, 0, 0, 0, 0, 0};
  short8 hm = zz, hp = zz;
  short8 h0 = *(const short8*)base;
  if (t > 0)      hm = *(const short8*)(base - 1024);
  if (t < Tt - 1) hp = *(const short8*)(base + 1024);
  short8 o;
#pragma unroll
  for (int j = 0; j < 8; ++j) {
    const int cj = c + j;
    float val = b2f(hm[j]) * w2[cj * 3 + 0]
              + b2f(h0[j]) * w2[cj * 3 + 1]
              + b2f(hp[j]) * w2[cj * 3 + 2]
              + b2[cj];
    o[j] = f2b(val);
  }
  *(short8*)(out + (size_t)bt * Cc + c) = o;
}

// ---------------------------------------------------------------------------
// Depthwise conv + transpose: outT[b,c,t] (bf16). H row stride 1024.
// grid (T/32, 512/64, B), block 256.
// ---------------------------------------------------------------------------
__global__ __launch_bounds__(256)
void dwt_kernel(const short* __restrict__ H, const float* __restrict__ w2,
                const float* __restrict__ b2, short* __restrict__ outT, int colOff)
{
  const int b  = blockIdx.z;
  const int c  = blockIdx.y * 64 + (threadIdx.x & 63);
  const int tb = blockIdx.x * 32 + (threadIdx.x >> 6) * 8;
  const short* base = H + ((size_t)b * Tt) * 1024 + colOff + c;
  float h[10];
#pragma unroll
  for (int i = 0; i < 10; ++i) {
    const int t = tb - 1 + i;
    h[i] = (t >= 0 && t < Tt) ? b2f(base[(size_t)t * 1024]) : 0.f;
  }
  const float w0 = w2[c * 3 + 0];
  const float w1 = w2[c * 3 + 1];
  const float wp = w2[c * 3 + 2];
  const float bb = b2[c];
  short8 o;
#pragma unroll
  for (int j = 0; j < 8; ++j)
    o[j] = f2b(h[j] * w0 + h[j + 1] * w1 + h[j + 2] * wp + bb);
  *(short8*)(outT + ((size_t)b * Cc + c) * Tt + tb) = o;
}

// ---------------------------------------------------------------------------
// In-place row softmax over rows of length T=2048 (bf16). One block per row.
// ---------------------------------------------------------------------------
__global__ __launch_bounds__(256)
void softmax_kernel(short* __restrict__ S)
{
  __shared__ float red[4];
  const size_t row = blockIdx.x;
  short8* p = (short8*)(S + row * (size_t)Tt) + threadIdx.x;
  short8 v = *p;
  float x[8];
  float mx = -1e30f;
#pragma unroll
  for (int j = 0; j < 8; ++j) { x[j] = b2f(v[j]); mx = fmaxf(mx, x[j]); }
#pragma unroll
  for (int off = 32; off > 0; off >>= 1) mx = fmaxf(mx, __shfl_xor(mx, off, 64));
  const int wvi = threadIdx.x >> 6;
  if ((threadIdx.x & 63) == 0) red[wvi] = mx;
  __syncthreads();
  mx = fmaxf(fmaxf(red[0], red[1]), fmaxf(red[2], red[3]));
  __syncthreads();
  float s = 0.f;
#pragma unroll
  for (int j = 0; j < 8; ++j) { x[j] = __expf(x[j] - mx); s += x[j]; }
#pragma unroll
  for (int off = 32; off > 0; off >>= 1) s += __shfl_xor(s, off, 64);
  if ((threadIdx.x & 63) == 0) red[wvi] = s;
  __syncthreads();
  const float inv = 1.f / (red[0] + red[1] + red[2] + red[3]);
  short8 o;
#pragma unroll
  for (int j = 0; j < 8; ++j) o[j] = f2b(x[j] * inv);
  *p = o;
}

// ---------------------------------------------------------------------------
extern "C" void kernel_launch(void* const* d_in, const int* in_sizes, int n_in,
                              void* d_out, int out_size, void* d_ws, size_t ws_size,
                              hipStream_t stream)
{
  const float* x_l    = (const float*)d_in[0];
  const float* x_r    = (const float*)d_in[1];
  const float* lp1_w1 = (const float*)d_in[2];
  const float* lp1_b1 = (const float*)d_in[3];
  const float* lp1_w2 = (const float*)d_in[4];
  const float* lp1_b2 = (const float*)d_in[5];
  const float* rp1_w1 = (const float*)d_in[6];
  const float* rp1_b1 = (const float*)d_in[7];
  const float* rp1_w2 = (const float*)d_in[8];
  const float* rp1_b2 = (const float*)d_in[9];
  const float* lp2_w1 = (const float*)d_in[10];
  const float* lp2_b1 = (const float*)d_in[11];
  const float* lp2_w2 = (const float*)d_in[12];
  const float* lp2_b2 = (const float*)d_in[13];
  const float* rp2_w1 = (const float*)d_in[14];
  const float* rp2_b1 = (const float*)d_in[15];
  const float* rp2_w2 = (const float*)d_in[16];
  const float* rp2_b2 = (const float*)d_in[17];
  const float* lp3_w  = (const float*)d_in[18];
  const float* lp3_b  = (const float*)d_in[19];
  const float* rp3_w  = (const float*)d_in[20];
  const float* rp3_b  = (const float*)d_in[21];

  short* ws = (short*)d_ws;
  const size_t SZ = (size_t)Bb * Tt * Cc;    // 8,388,608 bf16 elems (16.78 MB)
  short* Ql  = ws;
  short* Qr  = ws + SZ;
  short* VTl = ws + 2 * SZ;
  short* VTr = ws + 3 * SZ;
  short* Fb  = ws + 4 * SZ;
  short* Sb  = ws + 5 * SZ;                  // scores; plan A 4*SZ, plan B 2*SZ
  short* H   = Sb;                           // fused proj out (2*SZ), phase 1 only

  const size_t W_PAIR = 524288, W_SING = 262144;
  const size_t tail_elems = 2 * W_PAIR + 2 * W_SING + 2 * 2048 + 65536;
  const bool planA = ws_size >= 2 * (9 * SZ + tail_elems);   // ~154.3 MB
  const size_t tail = planA ? 9 * SZ : 7 * SZ;
  short* Wl  = ws + tail;
  short* Wr  = Wl + W_PAIR;
  short* W3l = Wr + W_PAIR;
  short* W3r = W3l + W_SING;
  float* BL  = (float*)(W3r + W_SING);
  float* BR  = BL + 1024;

  float* out_l = (float*)d_out;
  float* out_r = (float*)d_out + SZ;

  const float scale = 0.04419417382415922f;  // 512^-0.5
  const int MT = Bb * Tt;                    // 16384
  const long long sQ = (long long)Tt * Cc;
  const long long sS = (long long)Tt * Tt;
  const int nz = planA ? 8 : 4;
  const int ng = planA ? 1 : 2;

  dim3 blk(256);

  // ---- phase 0: pack weights ----
  pack_all<<<6152, blk, 0, stream>>>(lp1_w1, lp2_w1, rp1_w1, rp2_w1, lp3_w, rp3_w,
                                     lp1_b1, lp2_b1, rp1_b1, rp2_b1,
                                     Wl, Wr, W3l, W3r, BL, BR);

  // ---- phase 1: fused pointwise proj (N=1024) -> depthwise convs ----
  gemm_bt<0><<<dim3(8, 128, 1), blk, 0, stream>>>(x_l, Wl, H, BL, nullptr,
                                                  MT, 1024, Cc, 0, 0, 0, 1.f);
  dw_kernel <<<4096, blk, 0, stream>>>(H, lp1_w2, lp1_b2, Ql, 0);
  dwt_kernel<<<dim3(Tt / 32, 8, Bb), blk, 0, stream>>>(H, lp2_w2, lp2_b2, VTl, 512);

  gemm_bt<0><<<dim3(8, 128, 1), blk, 0, stream>>>(x_r, Wr, H, BR, nullptr,
                                                  MT, 1024, Cc, 0, 0, 0, 1.f);
  dw_kernel <<<4096, blk, 0, stream>>>(H, rp1_w2, rp1_b2, Qr, 0);
  dwt_kernel<<<dim3(Tt / 32, 8, Bb), blk, 0, stream>>>(H, rp2_w2, rp2_b2, VTr, 512);

  // ---- phase 2: attention, both directions ----
  for (int dir = 0; dir < 2; ++dir) {
    const short* Qa = dir == 0 ? Ql : Qr;
    const short* Qb = dir == 0 ? Qr : Ql;
    const short* Vt = dir == 0 ? VTr : VTl;
    const short* W3 = dir == 0 ? W3l : W3r;
    const float* b3 = dir == 0 ? lp3_b : rp3_b;
    const float* xr = dir == 0 ? x_l : x_r;
    float* outp     = dir == 0 ? out_l : out_r;

    for (int g = 0; g < ng; ++g) {
      const long long o = (long long)g * nz * sQ;
      gemm_bt<1><<<dim3(Tt / 128, Tt / 128, nz), blk, 0, stream>>>(
          Qa + o, Qb + o, Sb, nullptr, nullptr, Tt, Tt, Cc, sQ, sQ, sS, scale);
      softmax_kernel<<<nz * Tt, blk, 0, stream>>>(Sb);
      gemm_bt<2><<<dim3(Cc / 128, Tt / 128, nz), blk, 0, stream>>>(
          Sb, Vt + o, Fb + o, nullptr, nullptr, Tt, Cc, Tt, sS, sQ, sQ, 1.f);
    }
    gemm_bt<3><<<dim3(Cc / 128, MT / 128, 1), blk, 0, stream>>>(
        Fb, W3, outp, b3, xr, MT, Cc, Cc, 0, 0, 0, 1.f);
  }

  (void)in_sizes; (void)n_in; (void)out_size;
}

// Round 5
// 575.331 us; speedup vs baseline: 1.1757x; 1.1757x over previous
//
#include <hip/hip_runtime.h>
#include <stdint.h>

#define Bb 8
#define Tt 2048
#define Cc 512

typedef __attribute__((ext_vector_type(8))) short short8;
typedef __attribute__((ext_vector_type(4))) float f32x4;

__device__ __forceinline__ float b2f(short s) {
  unsigned int x = ((unsigned int)(unsigned short)s) << 16;
  return __builtin_bit_cast(float, x);
}
__device__ __forceinline__ short f2b(float f) {
  unsigned int x = __builtin_bit_cast(unsigned int, f);
  x += 0x7fffu + ((x >> 16) & 1u);   // round-to-nearest-even
  return (short)(x >> 16);
}

// Async global->LDS 16B copy. LDS dest is wave-uniform base + lane*16.
__device__ __forceinline__ void async_copy16(const short* g, short* l) {
  __builtin_amdgcn_global_load_lds(
      (const __attribute__((address_space(1))) unsigned int*)g,
      (__attribute__((address_space(3))) unsigned int*)l,
      16, 0, 0);
}

// ---------------------------------------------------------------------------
// GEMM: C[m,n] = epilogue( sum_k A[m,k] * B[n,k] )   (B row-major N x K, bf16)
// MODE 0: A fp32 (manual convert-stage), C bf16, +bias[n]     (pointwise)
// MODE 1: A bf16 async,                  C bf16, *scale       (scores)
// MODE 2: A bf16 async,                  C bf16               (P@V)
// MODE 3: A bf16 async,                  C fp32, +bias+resid  (out proj)
// 128x128 tile, BK=64, 4 waves 2x2, wave tile 64x64 via 4x4 MFMA 16x16x32.
//
// LDS layout (m-major, row-XOR swizzle): 16B chunk (m,kc) at chunk index
// m*8 + (kc ^ (m&7)).  Async staging: lane l of wave w, round r loads
// m = r*32 + w*8 + (l>>3), kc = (l&7) ^ (m&7)  -> the 8 lanes of a row fetch
// the SAME 128B segment (permuted) = coalesced, and LDS dest is exactly
// base + l*16.  Fragment reads (ma,kcr) hit all 32 banks 2-way = conflict-free
// [m136].
// ---------------------------------------------------------------------------
template<int MODE>
__global__ __launch_bounds__(256, 4)
void gemm_bt(const void* __restrict__ Av, const void* __restrict__ Bv,
             void* __restrict__ Cv, const float* __restrict__ bias,
             const float* __restrict__ resid,
             int M, int N, int K,
             long long sA, long long sB, long long sC, float scale)
{
  __shared__ __align__(16) short ldsA[128 * 64];
  __shared__ __align__(16) short ldsB[128 * 64];
  const int tid  = threadIdx.x;
  const int lane = tid & 63;
  const int wv   = tid >> 6;
  const int bm = blockIdx.y * 128;
  const int bn = blockIdx.x * 128;
  const long long zoA = (long long)blockIdx.z * sA;
  const long long zoB = (long long)blockIdx.z * sB;
  const long long zoC = (long long)blockIdx.z * sC;
  const int wm = (wv >> 1) << 6;
  const int wn = (wv & 1) << 6;

  f32x4 zero4 = {0.f, 0.f, 0.f, 0.f};
  f32x4 acc[4][4];
#pragma unroll
  for (int i = 0; i < 4; ++i)
#pragma unroll
    for (int j = 0; j < 4; ++j)
      acc[i][j] = zero4;

  // async staging mapping (per round r): coalesced row-segment, swizzled kc
  const int s_row = wv * 8 + (lane >> 3);          // + r*32
  const int s_kc  = (lane & 7) ^ (s_row & 7);      // (r*32 doesn't change m&7)
  const int sm  = tid >> 3;  // MODE 0 manual staging: row within round
  const int skc = tid & 7;

  for (int k0 = 0; k0 < K; k0 += 64) {
#pragma unroll
    for (int r = 0; r < 4; ++r) {
      const int m = r * 32 + s_row;
      async_copy16((const short*)Bv + zoB + (size_t)(bn + m) * K + k0 + s_kc * 8,
                   &ldsB[m >> 3 << 9]);   // (m/8)*8rows*64shorts, lane adds l*16B
    }
    if constexpr (MODE == 0) {
#pragma unroll
      for (int r = 0; r < 4; ++r) {
        const int m = r * 32 + sm;
        const float* ap = (const float*)Av + zoA + (size_t)(bm + m) * K + k0 + skc * 8;
        float4 f0 = *(const float4*)ap;
        float4 f1 = *(const float4*)(ap + 4);
        short8 av;
        av[0] = f2b(f0.x); av[1] = f2b(f0.y); av[2] = f2b(f0.z); av[3] = f2b(f0.w);
        av[4] = f2b(f1.x); av[5] = f2b(f1.y); av[6] = f2b(f1.z); av[7] = f2b(f1.w);
        *(short8*)&ldsA[((m << 3) + (skc ^ (m & 7))) << 3] = av;
      }
    } else {
#pragma unroll
      for (int r = 0; r < 4; ++r) {
        const int m = r * 32 + s_row;
        async_copy16((const short*)Av + zoA + (size_t)(bm + m) * K + k0 + s_kc * 8,
                     &ldsA[m >> 3 << 9]);
      }
    }
    __syncthreads();
#pragma unroll
    for (int kk = 0; kk < 2; ++kk) {
      const int kcr = (kk << 2) + (lane >> 4);
      short8 af[4], bfv[4];
#pragma unroll
      for (int i = 0; i < 4; ++i) {
        const int ma = wm + i * 16 + (lane & 15);
        const int nb = wn + i * 16 + (lane & 15);
        af[i]  = *(const short8*)&ldsA[((ma << 3) + (kcr ^ (ma & 7))) << 3];
        bfv[i] = *(const short8*)&ldsB[((nb << 3) + (kcr ^ (nb & 7))) << 3];
      }
#pragma unroll
      for (int i = 0; i < 4; ++i)
#pragma unroll
        for (int j = 0; j < 4; ++j)
          acc[i][j] = __builtin_amdgcn_mfma_f32_16x16x32_bf16(af[i], bfv[j], acc[i][j], 0, 0, 0);
    }
    __syncthreads();
  }

  // C/D layout: col = lane&15, row = (lane>>4)*4 + reg  [measured m89/m91]
#pragma unroll
  for (int i = 0; i < 4; ++i) {
    const int row0 = bm + wm + i * 16 + ((lane >> 4) << 2);
#pragma unroll
    for (int j = 0; j < 4; ++j) {
      const int n = bn + wn + j * 16 + (lane & 15);
      float badd = 0.f;
      if (MODE == 0 || MODE == 3) badd = bias[n];
#pragma unroll
      for (int r = 0; r < 4; ++r) {
        float val = acc[i][j][r];
        if (MODE == 1) val *= scale;
        if (MODE == 0) val += badd;
        if constexpr (MODE == 3) {
          val += badd + resid[zoC + (size_t)(row0 + r) * N + n];
          ((float*)Cv)[zoC + (size_t)(row0 + r) * N + n] = val;
        } else {
          ((short*)Cv)[zoC + (size_t)(row0 + r) * N + n] = f2b(val);
        }
      }
    }
  }
}

// ---------------------------------------------------------------------------
// One-shot weight/bias packing: fp32 -> bf16, proj pairs concatenated to N=1024.
// ---------------------------------------------------------------------------
__global__ __launch_bounds__(256)
void pack_all(const float* __restrict__ lw1a, const float* __restrict__ lw1b,
              const float* __restrict__ rw1a, const float* __restrict__ rw1b,
              const float* __restrict__ w3lf, const float* __restrict__ w3rf,
              const float* __restrict__ lb1a, const float* __restrict__ lb1b,
              const float* __restrict__ rb1a, const float* __restrict__ rb1b,
              short* __restrict__ Wl, short* __restrict__ Wr,
              short* __restrict__ W3l, short* __restrict__ W3r,
              float* __restrict__ BL, float* __restrict__ BR)
{
  const int i = blockIdx.x * 256 + threadIdx.x;
  if (i < 524288) {
    Wl[i] = f2b(i < 262144 ? lw1a[i] : lw1b[i - 262144]);
  } else if (i < 1048576) {
    const int j = i - 524288;
    Wr[j] = f2b(j < 262144 ? rw1a[j] : rw1b[j - 262144]);
  } else if (i < 1310720) {
    W3l[i - 1048576] = f2b(w3lf[i - 1048576]);
  } else if (i < 1572864) {
    W3r[i - 1310720] = f2b(w3rf[i - 1310720]);
  } else if (i < 1573888) {
    const int j = i - 1572864;
    BL[j] = j < 512 ? lb1a[j] : lb1b[j - 512];
  } else if (i < 1574912) {
    const int j = i - 1573888;
    BR[j] = j < 512 ? rb1a[j] : rb1b[j - 512];
  }
}

// ---------------------------------------------------------------------------
// Depthwise conv k=3 pad=1 over T. H row stride 1024, slice [colOff,colOff+512).
// ---------------------------------------------------------------------------
__global__ __launch_bounds__(256)
void dw_kernel(const short* __restrict__ H, const float* __restrict__ w2,
               const float* __restrict__ b2, short* __restrict__ out, int colOff)
{
  const int idx = blockIdx.x * 256 + threadIdx.x;   // over B*T*512/8
  const int c8 = idx & 63;
  const int bt = idx >> 6;
  const int t  = bt & (Tt - 1);
  const int c  = c8 << 3;
  const short* base = H + (size_t)bt * 1024 + colOff + c;
  short8 zz = {0, 0, 0, 0, 0, 0, 0, 0};
  short8 hm = zz, hp = zz;
  short8 h0 = *(const short8*)base;
  if (t > 0)      hm = *(const short8*)(base - 1024);
  if (t < Tt - 1) hp = *(const short8*)(base + 1024);
  short8 o;
#pragma unroll
  for (int j = 0; j < 8; ++j) {
    const int cj = c + j;
    float val = b2f(hm[j]) * w2[cj * 3 + 0]
              + b2f(h0[j]) * w2[cj * 3 + 1]
              + b2f(hp[j]) * w2[cj * 3 + 2]
              + b2[cj];
    o[j] = f2b(val);
  }
  *(short8*)(out + (size_t)bt * Cc + c) = o;
}

// ---------------------------------------------------------------------------
// Depthwise conv + transpose: outT[b,c,t] (bf16). H row stride 1024.
// grid (T/32, 512/64, B), block 256.
// ---------------------------------------------------------------------------
__global__ __launch_bounds__(256)
void dwt_kernel(const short* __restrict__ H, const float* __restrict__ w2,
                const float* __restrict__ b2, short* __restrict__ outT, int colOff)
{
  const int b  = blockIdx.z;
  const int c  = blockIdx.y * 64 + (threadIdx.x & 63);
  const int tb = blockIdx.x * 32 + (threadIdx.x >> 6) * 8;
  const short* base = H + ((size_t)b * Tt) * 1024 + colOff + c;
  float h[10];
#pragma unroll
  for (int i = 0; i < 10; ++i) {
    const int t = tb - 1 + i;
    h[i] = (t >= 0 && t < Tt) ? b2f(base[(size_t)t * 1024]) : 0.f;
  }
  const float w0 = w2[c * 3 + 0];
  const float w1 = w2[c * 3 + 1];
  const float wp = w2[c * 3 + 2];
  const float bb = b2[c];
  short8 o;
#pragma unroll
  for (int j = 0; j < 8; ++j)
    o[j] = f2b(h[j] * w0 + h[j + 1] * w1 + h[j + 2] * wp + bb);
  *(short8*)(outT + ((size_t)b * Cc + c) * Tt + tb) = o;
}

// ---------------------------------------------------------------------------
// In-place row softmax over rows of length T=2048 (bf16). One block per row.
// ---------------------------------------------------------------------------
__global__ __launch_bounds__(256)
void softmax_kernel(short* __restrict__ S)
{
  __shared__ float red[4];
  const size_t row = blockIdx.x;
  short8* p = (short8*)(S + row * (size_t)Tt) + threadIdx.x;
  short8 v = *p;
  float x[8];
  float mx = -1e30f;
#pragma unroll
  for (int j = 0; j < 8; ++j) { x[j] = b2f(v[j]); mx = fmaxf(mx, x[j]); }
#pragma unroll
  for (int off = 32; off > 0; off >>= 1) mx = fmaxf(mx, __shfl_xor(mx, off, 64));
  const int wvi = threadIdx.x >> 6;
  if ((threadIdx.x & 63) == 0) red[wvi] = mx;
  __syncthreads();
  mx = fmaxf(fmaxf(red[0], red[1]), fmaxf(red[2], red[3]));
  __syncthreads();
  float s = 0.f;
#pragma unroll
  for (int j = 0; j < 8; ++j) { x[j] = __expf(x[j] - mx); s += x[j]; }
#pragma unroll
  for (int off = 32; off > 0; off >>= 1) s += __shfl_xor(s, off, 64);
  if ((threadIdx.x & 63) == 0) red[wvi] = s;
  __syncthreads();
  const float inv = 1.f / (red[0] + red[1] + red[2] + red[3]);
  short8 o;
#pragma unroll
  for (int j = 0; j < 8; ++j) o[j] = f2b(x[j] * inv);
  *p = o;
}

// ---------------------------------------------------------------------------
extern "C" void kernel_launch(void* const* d_in, const int* in_sizes, int n_in,
                              void* d_out, int out_size, void* d_ws, size_t ws_size,
                              hipStream_t stream)
{
  const float* x_l    = (const float*)d_in[0];
  const float* x_r    = (const float*)d_in[1];
  const float* lp1_w1 = (const float*)d_in[2];
  const float* lp1_b1 = (const float*)d_in[3];
  const float* lp1_w2 = (const float*)d_in[4];
  const float* lp1_b2 = (const float*)d_in[5];
  const float* rp1_w1 = (const float*)d_in[6];
  const float* rp1_b1 = (const float*)d_in[7];
  const float* rp1_w2 = (const float*)d_in[8];
  const float* rp1_b2 = (const float*)d_in[9];
  const float* lp2_w1 = (const float*)d_in[10];
  const float* lp2_b1 = (const float*)d_in[11];
  const float* lp2_w2 = (const float*)d_in[12];
  const float* lp2_b2 = (const float*)d_in[13];
  const float* rp2_w1 = (const float*)d_in[14];
  const float* rp2_b1 = (const float*)d_in[15];
  const float* rp2_w2 = (const float*)d_in[16];
  const float* rp2_b2 = (const float*)d_in[17];
  const float* lp3_w  = (const float*)d_in[18];
  const float* lp3_b  = (const float*)d_in[19];
  const float* rp3_w  = (const float*)d_in[20];
  const float* rp3_b  = (const float*)d_in[21];

  short* ws = (short*)d_ws;
  const size_t SZ = (size_t)Bb * Tt * Cc;    // 8,388,608 bf16 elems (16.78 MB)
  short* Ql  = ws;
  short* Qr  = ws + SZ;
  short* VTl = ws + 2 * SZ;
  short* VTr = ws + 3 * SZ;
  short* Fb  = ws + 4 * SZ;
  short* Sb  = ws + 5 * SZ;                  // scores; plan A 4*SZ, plan B 2*SZ
  short* H   = Sb;                           // fused proj out (2*SZ), phase 1 only

  const size_t W_PAIR = 524288, W_SING = 262144;
  const size_t tail_elems = 2 * W_PAIR + 2 * W_SING + 2 * 2048 + 65536;
  const bool planA = ws_size >= 2 * (9 * SZ + tail_elems);   // ~154.3 MB
  const size_t tail = planA ? 9 * SZ : 7 * SZ;
  short* Wl  = ws + tail;
  short* Wr  = Wl + W_PAIR;
  short* W3l = Wr + W_PAIR;
  short* W3r = W3l + W_SING;
  float* BL  = (float*)(W3r + W_SING);
  float* BR  = BL + 1024;

  float* out_l = (float*)d_out;
  float* out_r = (float*)d_out + SZ;

  const float scale = 0.04419417382415922f;  // 512^-0.5
  const int MT = Bb * Tt;                    // 16384
  const long long sQ = (long long)Tt * Cc;
  const long long sS = (long long)Tt * Tt;
  const int nz = planA ? 8 : 4;
  const int ng = planA ? 1 : 2;

  dim3 blk(256);

  // ---- phase 0: pack weights ----
  pack_all<<<6152, blk, 0, stream>>>(lp1_w1, lp2_w1, rp1_w1, rp2_w1, lp3_w, rp3_w,
                                     lp1_b1, lp2_b1, rp1_b1, rp2_b1,
                                     Wl, Wr, W3l, W3r, BL, BR);

  // ---- phase 1: fused pointwise proj (N=1024) -> depthwise convs ----
  gemm_bt<0><<<dim3(8, 128, 1), blk, 0, stream>>>(x_l, Wl, H, BL, nullptr,
                                                  MT, 1024, Cc, 0, 0, 0, 1.f);
  dw_kernel <<<4096, blk, 0, stream>>>(H, lp1_w2, lp1_b2, Ql, 0);
  dwt_kernel<<<dim3(Tt / 32, 8, Bb), blk, 0, stream>>>(H, lp2_w2, lp2_b2, VTl, 512);

  gemm_bt<0><<<dim3(8, 128, 1), blk, 0, stream>>>(x_r, Wr, H, BR, nullptr,
                                                  MT, 1024, Cc, 0, 0, 0, 1.f);
  dw_kernel <<<4096, blk, 0, stream>>>(H, rp1_w2, rp1_b2, Qr, 0);
  dwt_kernel<<<dim3(Tt / 32, 8, Bb), blk, 0, stream>>>(H, rp2_w2, rp2_b2, VTr, 512);

  // ---- phase 2: attention, both directions ----
  for (int dir = 0; dir < 2; ++dir) {
    const short* Qa = dir == 0 ? Ql : Qr;
    const short* Qb = dir == 0 ? Qr : Ql;
    const short* Vt = dir == 0 ? VTr : VTl;
    const short* W3 = dir == 0 ? W3l : W3r;
    const float* b3 = dir == 0 ? lp3_b : rp3_b;
    const float* xr = dir == 0 ? x_l : x_r;
    float* outp     = dir == 0 ? out_l : out_r;

    for (int g = 0; g < ng; ++g) {
      const long long o = (long long)g * nz * sQ;
      gemm_bt<1><<<dim3(Tt / 128, Tt / 128, nz), blk, 0, stream>>>(
          Qa + o, Qb + o, Sb, nullptr, nullptr, Tt, Tt, Cc, sQ, sQ, sS, scale);
      softmax_kernel<<<nz * Tt, blk, 0, stream>>>(Sb);
      gemm_bt<2><<<dim3(Cc / 128, Tt / 128, nz), blk, 0, stream>>>(
          Sb, Vt + o, Fb + o, nullptr, nullptr, Tt, Cc, Tt, sS, sQ, sQ, 1.f);
    }
    gemm_bt<3><<<dim3(Cc / 128, MT / 128, 1), blk, 0, stream>>>(
        Fb, W3, outp, b3, xr, MT, Cc, Cc, 0, 0, 0, 1.f);
  }

  (void)in_sizes; (void)n_in; (void)out_size;
}